// Round 8
// baseline (1343.329 us; speedup 1.0000x reference)
//
#include <hip/hip_runtime.h>
#include <hip/hip_fp16.h>
#include <math.h>

#define N_NODES 100000
#define N_EDGES 1600000
#define HDIM    128
#define NCLS    10
#define NGRAPH  1000
#define GEMM_BLOCKS  ((N_NODES + 127) / 128)   // 782
#define GEMM_THREADS (GEMM_BLOCKS * 256)       // 200192; ceil(E/threads)=8 edges/thread
#define NSLICE  4                              // 32 features = 64 B fp16 per slice-row
#define NCHUNK  (N_NODES / 16)                 // 6250 chunks of 16 nodes
#define AGG_BLOCKS (NSLICE * NCHUNK)           // 25000
// HW_REG_XCC_ID (id=20, gfx940+): imm = id | (offset<<6) | ((size-1)<<11)
#define XCC_HWREG (20 | (31 << 11))

// slice-major half index for (node, feature k):
// region slice=k>>5 is contiguous [N_NODES x 32] halves -> 64 B aligned rows.
#define HIDX(sl, node, off) ((((size_t)(sl) * N_NODES + (node)) << 5) + (off))

static __device__ __forceinline__ float elu1(float x) {
  return x > 0.f ? x : (__expf(x) - 1.f);
}

// ---------- GEMM body: Ch(slice-major fp16) = A @ W[128,128](f32) ----------
// 128x128 tile/block, W whole in LDS (64 KB), 8x8 reg tile/thread, pipelined
// A loads. A is f32 row-major (layer 0 input x) or fp16 slice-major (feat).
template <bool AHALF>
__device__ __forceinline__
void gemm_body(const void* __restrict__ Av, const float* __restrict__ W,
               __half* __restrict__ Ch, int nrows, float* Wl, int bid) {
  int tid = threadIdx.x;
  {
    const float4* W4 = (const float4*)W;
    float4* Wl4 = (float4*)Wl;
    for (int i = tid; i < 128 * 128 / 4; i += 256) Wl4[i] = W4[i];
  }
  __syncthreads();

  int ty = tid >> 4;
  int tx = tid & 15;
  int row0 = bid * 128 + ty * 8;

  int rows[8];
#pragma unroll
  for (int r = 0; r < 8; ++r) {
    int rr = row0 + r;
    if (rr > nrows - 1) rr = nrows - 1;  // clamp tail (stores are guarded)
    rows[r] = rr;
  }

  float4 acc0[8], acc1[8];
#pragma unroll
  for (int r = 0; r < 8; ++r) {
    acc0[r] = make_float4(0.f, 0.f, 0.f, 0.f);
    acc1[r] = make_float4(0.f, 0.f, 0.f, 0.f);
  }

#define FMA8(xs, w0, w1, r)                     \
  acc0[r].x = fmaf(xs, w0.x, acc0[r].x);        \
  acc0[r].y = fmaf(xs, w0.y, acc0[r].y);        \
  acc0[r].z = fmaf(xs, w0.z, acc0[r].z);        \
  acc0[r].w = fmaf(xs, w0.w, acc0[r].w);        \
  acc1[r].x = fmaf(xs, w1.x, acc1[r].x);        \
  acc1[r].y = fmaf(xs, w1.y, acc1[r].y);        \
  acc1[r].z = fmaf(xs, w1.z, acc1[r].z);        \
  acc1[r].w = fmaf(xs, w1.w, acc1[r].w);

  if constexpr (AHALF) {
    const __half* Ah = (const __half*)Av;
    uint4 cur[8], nxt[8];
#pragma unroll
    for (int r = 0; r < 8; ++r) cur[r] = *(const uint4*)&Ah[HIDX(0, rows[r], 0)];
    for (int k = 0; k < 128; k += 8) {
      if (k + 8 < 128) {
        int kn = k + 8;
#pragma unroll
        for (int r = 0; r < 8; ++r)
          nxt[r] = *(const uint4*)&Ah[HIDX(kn >> 5, rows[r], kn & 31)];
      }
#pragma unroll
      for (int kk = 0; kk < 8; ++kk) {
        const float* wrow = &Wl[(k + kk) * 128];
        float4 w0 = *(const float4*)(wrow + tx * 4);
        float4 w1 = *(const float4*)(wrow + 64 + tx * 4);
#pragma unroll
        for (int r = 0; r < 8; ++r) {
          __half2 hp = ((const __half2*)&cur[r])[kk >> 1];
          float xs = (kk & 1) ? __high2float(hp) : __low2float(hp);
          FMA8(xs, w0, w1, r)
        }
      }
#pragma unroll
      for (int r = 0; r < 8; ++r) cur[r] = nxt[r];
    }
  } else {
    const float* Af = (const float*)Av;
    float4 xa[8], xb[8];
#pragma unroll
    for (int r = 0; r < 8; ++r) xa[r] = *(const float4*)(Af + (size_t)rows[r] * HDIM);
    for (int k = 0; k < 128; k += 8) {
#pragma unroll
      for (int r = 0; r < 8; ++r)
        xb[r] = *(const float4*)(Af + (size_t)rows[r] * HDIM + k + 4);
#pragma unroll
      for (int kk = 0; kk < 4; ++kk) {
        const float* wrow = &Wl[(k + kk) * 128];
        float4 w0 = *(const float4*)(wrow + tx * 4);
        float4 w1 = *(const float4*)(wrow + 64 + tx * 4);
#pragma unroll
        for (int r = 0; r < 8; ++r) {
          float xs = ((const float*)&xa[r])[kk];
          FMA8(xs, w0, w1, r)
        }
      }
      if (k + 8 < 128) {
#pragma unroll
        for (int r = 0; r < 8; ++r)
          xa[r] = *(const float4*)(Af + (size_t)rows[r] * HDIM + k + 8);
      }
#pragma unroll
      for (int kk = 0; kk < 4; ++kk) {
        const float* wrow = &Wl[(k + 4 + kk) * 128];
        float4 w0 = *(const float4*)(wrow + tx * 4);
        float4 w1 = *(const float4*)(wrow + 64 + tx * 4);
#pragma unroll
        for (int r = 0; r < 8; ++r) {
          float xs = ((const float*)&xb[r])[kk];
          FMA8(xs, w0, w1, r)
        }
      }
    }
  }
#undef FMA8

  // slice-major store: cols [4tx,4tx+4) -> slice tx>>3; cols 64+4tx -> +2
  int sl0 = tx >> 3;
  int offh = (4 * tx) & 31;
#pragma unroll
  for (int r = 0; r < 8; ++r) {
    int rrow = row0 + r;
    if (rrow < nrows) {
      __half2 l0 = __floats2half2_rn(acc0[r].x, acc0[r].y);
      __half2 l1 = __floats2half2_rn(acc0[r].z, acc0[r].w);
      __half2 h0 = __floats2half2_rn(acc1[r].x, acc1[r].y);
      __half2 h1 = __floats2half2_rn(acc1[r].z, acc1[r].w);
      uint2 p0, p1;
      p0.x = *(unsigned*)&l0; p0.y = *(unsigned*)&l1;
      p1.x = *(unsigned*)&h0; p1.y = *(unsigned*)&h1;
      *(uint2*)&Ch[HIDX(sl0, rrow, offh)] = p0;
      *(uint2*)&Ch[HIDX(sl0 + 2, rrow, offh)] = p1;
    }
  }
}

// ---------- layer-0 GEMM with embedded histograms ----------
// (R6: vmcnt drains in-order so overlap is imperfect, but rank capture makes
// fill_csr atomic-free; kept.)
__global__ __launch_bounds__(256, 2)
void gemm0_hist(const float* __restrict__ A, const float* __restrict__ W,
                __half* __restrict__ Ch,
                const int* __restrict__ ei, const int* __restrict__ batch,
                int* __restrict__ cnt, int* __restrict__ gcnt,
                int* __restrict__ erank) {
  int gtid = blockIdx.x * 256 + threadIdx.x;
  int ranks[8];
#pragma unroll
  for (int k = 0; k < 8; ++k) {
    int e = gtid + k * GEMM_THREADS;
    if (e < N_EDGES) ranks[k] = atomicAdd(&cnt[ei[N_EDGES + e]], 1);
  }
  if (gtid < N_NODES) atomicAdd(&gcnt[batch[gtid]], 1);

  __shared__ float Wl[128 * 128];
  gemm_body<false>(A, W, Ch, N_NODES, Wl, blockIdx.x);

#pragma unroll
  for (int k = 0; k < 8; ++k) {
    int e = gtid + k * GEMM_THREADS;
    if (e < N_EDGES) erank[e] = ranks[k];
  }
}

__global__ __launch_bounds__(256, 2)
void gemm_h(const __half* __restrict__ A, const float* __restrict__ W,
            __half* __restrict__ Ch, int nrows) {
  __shared__ float Wl[128 * 128];
  gemm_body<true>(A, W, Ch, nrows, Wl, blockIdx.x);
}

// ---------- CSR build ----------

__global__ void scan_local(const int* __restrict__ cnt, int* __restrict__ off,
                           int* __restrict__ bsum, float* __restrict__ dinv, int n) {
  __shared__ int s[256];
  int t = threadIdx.x;
  int base = blockIdx.x * 1024 + t * 4;
  int v0 = (base + 0 < n) ? cnt[base + 0] : 0;
  int v1 = (base + 1 < n) ? cnt[base + 1] : 0;
  int v2 = (base + 2 < n) ? cnt[base + 2] : 0;
  int v3 = (base + 3 < n) ? cnt[base + 3] : 0;
  if (base + 0 < n) dinv[base + 0] = rsqrtf((float)(v0 + 1));
  if (base + 1 < n) dinv[base + 1] = rsqrtf((float)(v1 + 1));
  if (base + 2 < n) dinv[base + 2] = rsqrtf((float)(v2 + 1));
  if (base + 3 < n) dinv[base + 3] = rsqrtf((float)(v3 + 1));
  int sum = v0 + v1 + v2 + v3;
  s[t] = sum;
  __syncthreads();
#pragma unroll
  for (int d = 1; d < 256; d <<= 1) {
    int val = (t >= d) ? s[t - d] : 0;
    __syncthreads();
    s[t] += val;
    __syncthreads();
  }
  int run = s[t] - sum;
  if (base + 0 < n) off[base + 0] = run; run += v0;
  if (base + 1 < n) off[base + 1] = run; run += v1;
  if (base + 2 < n) off[base + 2] = run; run += v2;
  if (base + 3 < n) off[base + 3] = run;
  if (t == 255) bsum[blockIdx.x] = s[255];
}

__global__ void scan_blocks(const int* __restrict__ bsum, int* __restrict__ boff, int nb) {
  __shared__ int s[128];
  int t = threadIdx.x;
  int v = (t < nb) ? bsum[t] : 0;
  s[t] = v;
  __syncthreads();
#pragma unroll
  for (int d = 1; d < 128; d <<= 1) {
    int val = (t >= d) ? s[t - d] : 0;
    __syncthreads();
    s[t] += val;
    __syncthreads();
  }
  if (t < nb) boff[t] = s[t] - v;
}

__global__ void scan_add(int* __restrict__ off, const int* __restrict__ boff,
                         int n, int total) {
  int i = blockIdx.x * blockDim.x + threadIdx.x;
  if (i < n) {
    off[i] += boff[i >> 10];
  } else if (i == n) {
    off[n] = total;
  }
}

__global__ void fill_csr(const int* __restrict__ ei, const int* __restrict__ off,
                         const int* __restrict__ erank, int* __restrict__ csrc) {
  int e = blockIdx.x * blockDim.x + threadIdx.x;
  if (e >= N_EDGES) return;
  csrc[off[ei[N_EDGES + e]] + erank[e]] = ei[e];
}

// ---------- graph (pooling) ranges ----------

__global__ void gscan(const int* __restrict__ gcnt, int* __restrict__ goff) {
  __shared__ int s[256];
  int t = threadIdx.x;
  int base = t * 4;
  int v0 = (base + 0 < NGRAPH) ? gcnt[base + 0] : 0;
  int v1 = (base + 1 < NGRAPH) ? gcnt[base + 1] : 0;
  int v2 = (base + 2 < NGRAPH) ? gcnt[base + 2] : 0;
  int v3 = (base + 3 < NGRAPH) ? gcnt[base + 3] : 0;
  int sum = v0 + v1 + v2 + v3;
  s[t] = sum;
  __syncthreads();
#pragma unroll
  for (int d = 1; d < 256; d <<= 1) {
    int val = (t >= d) ? s[t - d] : 0;
    __syncthreads();
    s[t] += val;
    __syncthreads();
  }
  int run = s[t] - sum;
  if (base + 0 < NGRAPH) goff[base + 0] = run; run += v0;
  if (base + 1 < NGRAPH) goff[base + 1] = run; run += v1;
  if (base + 2 < NGRAPH) goff[base + 2] = run; run += v2;
  if (base + 3 < NGRAPH) goff[base + 3] = run;
  if (t == 255) goff[NGRAPH] = s[255];
}

// ---------- slice-parallel aggregation, XCC-affine ----------
// R7 post-mortem: blockIdx%8->XCD affinity failed AND 32 B strided slices
// wasted half of every 64 B miss sector (FETCH 683 MB). Fixes here:
// (1) slice-major layout: slice-rows are contiguous 64 B aligned -> misses
//     waste nothing; worst case (no affinity) == R6 traffic (~345 MB).
// (2) affinity by MEASUREMENT: block reads HW_REG_XCC_ID and pops a chunk
//     from its home slice's queue (fallback to neighbors when drained).
//     Exactly-once by atomic ticketing; correctness independent of XCC_ID.
// Per-XCD gather working set with affinity: 25.6/4 = 6.4 MB (~60% in 4 MB L2).
// Wave = 4 groups x 16 lanes; group owns one dst; lane owns half2 -> one
// contiguous 64 B gather per edge per group.
__global__ __launch_bounds__(256)
void aggregate_slice(const __half* __restrict__ h, const int* __restrict__ off,
                     const int* __restrict__ csrc, const float* __restrict__ dinv,
                     const float* __restrict__ bias, __half* __restrict__ out,
                     int* __restrict__ q) {
  __shared__ int sslice, schunk;
  if (threadIdx.x == 0) {
    int home = (int)(__builtin_amdgcn_s_getreg(XCC_HWREG) & 3u);
    int slice = -1, chunk = 0;
#pragma unroll
    for (int i = 0; i < NSLICE; ++i) {
      int ss = (home + i) & (NSLICE - 1);
      int c = atomicAdd(&q[ss], 1);
      if (c < NCHUNK) { slice = ss; chunk = c; break; }
    }
    sslice = slice; schunk = chunk;
  }
  __syncthreads();
  int slice = sslice;
  if (slice < 0) return;
  int node = schunk * 16 + (threadIdx.x >> 4);
  int j = threadIdx.x & 15;
  const __half2* h2 = (const __half2*)h;
  size_t sb = (size_t)slice * N_NODES;  // slice base, in 64 B rows

  int beg = off[node], end = off[node + 1];
  float a0 = 0.f, a1 = 0.f, c0 = 0.f, c1 = 0.f;

  int e = beg;
  for (; e + 4 <= end; e += 4) {
    int s0 = csrc[e + 0], s1 = csrc[e + 1], s2 = csrc[e + 2], s3 = csrc[e + 3];
    float w0 = dinv[s0], w1 = dinv[s1], w2 = dinv[s2], w3 = dinv[s3];
    float2 f0 = __half22float2(h2[(sb + s0) * 16 + j]);
    float2 f1 = __half22float2(h2[(sb + s1) * 16 + j]);
    float2 f2 = __half22float2(h2[(sb + s2) * 16 + j]);
    float2 f3 = __half22float2(h2[(sb + s3) * 16 + j]);
    a0 = fmaf(w0, f0.x, a0); a1 = fmaf(w0, f0.y, a1);
    c0 = fmaf(w1, f1.x, c0); c1 = fmaf(w1, f1.y, c1);
    a0 = fmaf(w2, f2.x, a0); a1 = fmaf(w2, f2.y, a1);
    c0 = fmaf(w3, f3.x, c0); c1 = fmaf(w3, f3.y, c1);
  }
  if (e + 2 <= end) {
    int s0 = csrc[e + 0], s1 = csrc[e + 1];
    float w0 = dinv[s0], w1 = dinv[s1];
    float2 f0 = __half22float2(h2[(sb + s0) * 16 + j]);
    float2 f1 = __half22float2(h2[(sb + s1) * 16 + j]);
    a0 = fmaf(w0, f0.x, a0); a1 = fmaf(w0, f0.y, a1);
    c0 = fmaf(w1, f1.x, c0); c1 = fmaf(w1, f1.y, c1);
    e += 2;
  }
  if (e < end) {
    int s0 = csrc[e];
    float w0 = dinv[s0];
    float2 f0 = __half22float2(h2[(sb + s0) * 16 + j]);
    a0 = fmaf(w0, f0.x, a0); a1 = fmaf(w0, f0.y, a1);
  }

  float dv = dinv[node];
  float2 vs = __half22float2(h2[(sb + node) * 16 + j]);
  float sx = (a0 + c0) + dv * vs.x;
  float sy = (a1 + c1) + dv * vs.y;

  float2 bb = ((const float2*)bias)[slice * 16 + j];
  float ox = elu1(fmaf(dv, sx, bb.x));
  float oy = elu1(fmaf(dv, sy, bb.y));
  ((__half2*)out)[(sb + node) * 16 + j] = __floats2half2_rn(ox, oy);
}

// ---------- fused max-pool + linear head + softmax ----------
__global__ void pool_head(const __half* __restrict__ feat, const int* __restrict__ goff,
                          const float* __restrict__ Wl, const float* __restrict__ bl,
                          float* __restrict__ out) {
  int g = blockIdx.x;
  int t = threadIdx.x;
  int beg = goff[g], end = goff[g + 1];
  size_t fb = ((size_t)(t >> 5) * N_NODES << 5) + (t & 31);  // slice-major

  float m0 = -INFINITY, m1 = -INFINITY, m2 = -INFINITY, m3 = -INFINITY;
  int i = beg;
  for (; i + 4 <= end; i += 4) {
    m0 = fmaxf(m0, __half2float(feat[fb + (size_t)(i + 0) * 32]));
    m1 = fmaxf(m1, __half2float(feat[fb + (size_t)(i + 1) * 32]));
    m2 = fmaxf(m2, __half2float(feat[fb + (size_t)(i + 2) * 32]));
    m3 = fmaxf(m3, __half2float(feat[fb + (size_t)(i + 3) * 32]));
  }
  for (; i < end; ++i) m0 = fmaxf(m0, __half2float(feat[fb + (size_t)i * 32]));
  float m = fmaxf(fmaxf(m0, m1), fmaxf(m2, m3));
  if (beg == end) m = 0.f;

  __shared__ float pl[HDIM];
  __shared__ float lg[NCLS];
  pl[t] = m;
  __syncthreads();

  if (t < NCLS) {
    float acc = bl[t];
#pragma unroll
    for (int f = 0; f < HDIM; ++f) acc = fmaf(pl[f], Wl[f * NCLS + t], acc);
    lg[t] = acc;
  }
  __syncthreads();

  if (t < NCLS) {
    float mx = lg[0];
#pragma unroll
    for (int c = 1; c < NCLS; ++c) mx = fmaxf(mx, lg[c]);
    float ssum = 0.f;
#pragma unroll
    for (int c = 0; c < NCLS; ++c) ssum += __expf(lg[c] - mx);
    out[g * NCLS + t] = __expf(lg[t] - mx) / ssum;
  }
}

// ---------- launch ----------

extern "C" void kernel_launch(void* const* d_in, const int* in_sizes, int n_in,
                              void* d_out, int out_size, void* d_ws, size_t ws_size,
                              hipStream_t stream) {
  const float* x    = (const float*)d_in[0];
  const int*   ei   = (const int*)d_in[1];
  const int*   batch= (const int*)d_in[2];
  const float* W0 = (const float*)d_in[3]; const float* b0 = (const float*)d_in[4];
  const float* W1 = (const float*)d_in[5]; const float* b1 = (const float*)d_in[6];
  const float* W2 = (const float*)d_in[7]; const float* b2 = (const float*)d_in[8];
  const float* Wl = (const float*)d_in[9]; const float* bl = (const float*)d_in[10];
  float* out = (float*)d_out;

  char* w = (char*)d_ws;
  auto alloc = [&](size_t bytes) {
    char* p = w;
    w += (bytes + 255) & ~(size_t)255;
    return p;
  };
  int*    cnt    = (int*)   alloc((size_t)N_NODES * 4);
  int*    off    = (int*)   alloc((size_t)(N_NODES + 1) * 4);
  float*  dinv   = (float*) alloc((size_t)N_NODES * 4);
  int*    bsum   = (int*)   alloc(128 * 4);
  int*    boff   = (int*)   alloc(128 * 4);
  int*    gcnt   = (int*)   alloc((size_t)NGRAPH * 4);
  int*    goff   = (int*)   alloc((size_t)(NGRAPH + 1) * 4);
  int*    qctr   = (int*)   alloc(3 * NSLICE * 4);
  int*    erank  = (int*)   alloc((size_t)N_EDGES * 4);
  int*    csrc   = (int*)   alloc((size_t)N_EDGES * 4);
  __half* hbuf   = (__half*)alloc((size_t)N_NODES * HDIM * 2);
  __half* feat   = (__half*)alloc((size_t)N_NODES * HDIM * 2);

  hipMemsetAsync(cnt, 0, (size_t)N_NODES * 4, stream);
  hipMemsetAsync(gcnt, 0, (size_t)NGRAPH * 4, stream);
  hipMemsetAsync(qctr, 0, 3 * NSLICE * 4, stream);

  // layer-0 GEMM with embedded degree/graph histograms
  gemm0_hist<<<GEMM_BLOCKS, 256, 0, stream>>>(x, W0, hbuf, ei, batch, cnt, gcnt, erank);

  int nb = (N_NODES + 1023) / 1024;
  scan_local<<<nb, 256, 0, stream>>>(cnt, off, bsum, dinv, N_NODES);
  scan_blocks<<<1, 128, 0, stream>>>(bsum, boff, nb);
  scan_add<<<(N_NODES + 1 + 255) / 256, 256, 0, stream>>>(off, boff, N_NODES, N_EDGES);
  fill_csr<<<(N_EDGES + 255) / 256, 256, 0, stream>>>(ei, off, erank, csrc);

  gscan<<<1, 256, 0, stream>>>(gcnt, goff);

  const float* bs[3] = {b0, b1, b2};
  aggregate_slice<<<AGG_BLOCKS, 256, 0, stream>>>(hbuf, off, csrc, dinv, bs[0], feat,
                                                  qctr + 0 * NSLICE);
  for (int l = 1; l < 3; ++l) {
    const float* Wcur = (l == 1) ? W1 : W2;
    gemm_h<<<GEMM_BLOCKS, 256, 0, stream>>>(feat, Wcur, hbuf, N_NODES);
    aggregate_slice<<<AGG_BLOCKS, 256, 0, stream>>>(hbuf, off, csrc, dinv, bs[l], feat,
                                                    qctr + l * NSLICE);
  }

  pool_head<<<NGRAPH, 128, 0, stream>>>(feat, goff, Wl, bl, out);
}

// Round 9
// 573.903 us; speedup vs baseline: 2.3407x; 2.3407x over previous
//
#include <hip/hip_runtime.h>
#include <hip/hip_fp16.h>
#include <math.h>

#define N_NODES 100000
#define N_EDGES 1600000
#define HDIM    128
#define NCLS    10
#define NGRAPH  1000
#define GEMM_BLOCKS  ((N_NODES + 127) / 128)   // 782
// radix-bucket CSR build
#define BSHIFT   9
#define BUCKW    (1 << BSHIFT)                 // 512 nodes / bucket
#define NB       ((N_NODES + BUCKW - 1) >> BSHIFT)   // 196
#define EPB      8192                          // edges per chunk block
#define NCHUNKS  ((N_EDGES + EPB - 1) / EPB)   // 196

static __device__ __forceinline__ float elu1(float x) {
  return x > 0.f ? x : (__expf(x) - 1.f);
}

// ---------- GEMM body: Ch[n,128](fp16) = A[n,128] @ W[128,128](f32) ----------
// (R6's verified shape: 128x128 tile, W in LDS, 8x8 reg tile, pipelined A.)
template <bool AHALF>
__device__ __forceinline__
void gemm_body(const void* __restrict__ Av, const float* __restrict__ W,
               __half* __restrict__ Ch, int nrows, float* Wl, int bid) {
  int tid = threadIdx.x;
  {
    const float4* W4 = (const float4*)W;
    float4* Wl4 = (float4*)Wl;
    for (int i = tid; i < 128 * 128 / 4; i += 256) Wl4[i] = W4[i];
  }
  __syncthreads();

  int ty = tid >> 4;
  int tx = tid & 15;
  int row0 = bid * 128 + ty * 8;

  size_t rbase[8];
#pragma unroll
  for (int r = 0; r < 8; ++r) {
    int rr = row0 + r;
    if (rr > nrows - 1) rr = nrows - 1;  // clamp tail (stores are guarded)
    rbase[r] = (size_t)rr * HDIM;
  }

  float4 acc0[8], acc1[8];
#pragma unroll
  for (int r = 0; r < 8; ++r) {
    acc0[r] = make_float4(0.f, 0.f, 0.f, 0.f);
    acc1[r] = make_float4(0.f, 0.f, 0.f, 0.f);
  }

#define FMA8(xs, w0, w1, r)                     \
  acc0[r].x = fmaf(xs, w0.x, acc0[r].x);        \
  acc0[r].y = fmaf(xs, w0.y, acc0[r].y);        \
  acc0[r].z = fmaf(xs, w0.z, acc0[r].z);        \
  acc0[r].w = fmaf(xs, w0.w, acc0[r].w);        \
  acc1[r].x = fmaf(xs, w1.x, acc1[r].x);        \
  acc1[r].y = fmaf(xs, w1.y, acc1[r].y);        \
  acc1[r].z = fmaf(xs, w1.z, acc1[r].z);        \
  acc1[r].w = fmaf(xs, w1.w, acc1[r].w);

  if constexpr (AHALF) {
    const __half* Ah = (const __half*)Av;
    uint4 cur[8], nxt[8];
#pragma unroll
    for (int r = 0; r < 8; ++r) cur[r] = *(const uint4*)(Ah + rbase[r]);
    for (int k = 0; k < 128; k += 8) {
      if (k + 8 < 128) {
#pragma unroll
        for (int r = 0; r < 8; ++r) nxt[r] = *(const uint4*)(Ah + rbase[r] + k + 8);
      }
#pragma unroll
      for (int kk = 0; kk < 8; ++kk) {
        const float* wrow = &Wl[(k + kk) * 128];
        float4 w0 = *(const float4*)(wrow + tx * 4);
        float4 w1 = *(const float4*)(wrow + 64 + tx * 4);
#pragma unroll
        for (int r = 0; r < 8; ++r) {
          __half2 hp = ((const __half2*)&cur[r])[kk >> 1];
          float xs = (kk & 1) ? __high2float(hp) : __low2float(hp);
          FMA8(xs, w0, w1, r)
        }
      }
#pragma unroll
      for (int r = 0; r < 8; ++r) cur[r] = nxt[r];
    }
  } else {
    const float* Af = (const float*)Av;
    float4 xa[8], xb[8];
#pragma unroll
    for (int r = 0; r < 8; ++r) xa[r] = *(const float4*)(Af + rbase[r]);
    for (int k = 0; k < 128; k += 8) {
#pragma unroll
      for (int r = 0; r < 8; ++r) xb[r] = *(const float4*)(Af + rbase[r] + k + 4);
#pragma unroll
      for (int kk = 0; kk < 4; ++kk) {
        const float* wrow = &Wl[(k + kk) * 128];
        float4 w0 = *(const float4*)(wrow + tx * 4);
        float4 w1 = *(const float4*)(wrow + 64 + tx * 4);
#pragma unroll
        for (int r = 0; r < 8; ++r) {
          float xs = ((const float*)&xa[r])[kk];
          FMA8(xs, w0, w1, r)
        }
      }
      if (k + 8 < 128) {
#pragma unroll
        for (int r = 0; r < 8; ++r) xa[r] = *(const float4*)(Af + rbase[r] + k + 8);
      }
#pragma unroll
      for (int kk = 0; kk < 4; ++kk) {
        const float* wrow = &Wl[(k + 4 + kk) * 128];
        float4 w0 = *(const float4*)(wrow + tx * 4);
        float4 w1 = *(const float4*)(wrow + 64 + tx * 4);
#pragma unroll
        for (int r = 0; r < 8; ++r) {
          float xs = ((const float*)&xb[r])[kk];
          FMA8(xs, w0, w1, r)
        }
      }
    }
  }
#undef FMA8

#pragma unroll
  for (int r = 0; r < 8; ++r) {
    int rrow = row0 + r;
    if (rrow < nrows) {
      __half2 l0 = __floats2half2_rn(acc0[r].x, acc0[r].y);
      __half2 l1 = __floats2half2_rn(acc0[r].z, acc0[r].w);
      __half2 h0 = __floats2half2_rn(acc1[r].x, acc1[r].y);
      __half2 h1 = __floats2half2_rn(acc1[r].z, acc1[r].w);
      uint2 p0, p1;
      p0.x = *(unsigned*)&l0; p0.y = *(unsigned*)&l1;
      p1.x = *(unsigned*)&h0; p1.y = *(unsigned*)&h1;
      *(uint2*)&Ch[(size_t)rrow * HDIM + tx * 4] = p0;
      *(uint2*)&Ch[(size_t)rrow * HDIM + 64 + tx * 4] = p1;
    }
  }
}

__global__ __launch_bounds__(256, 2)
void gemm_f(const float* __restrict__ A, const float* __restrict__ W,
            __half* __restrict__ Ch, int nrows) {
  __shared__ float Wl[128 * 128];
  gemm_body<false>(A, W, Ch, nrows, Wl, blockIdx.x);
}

__global__ __launch_bounds__(256, 2)
void gemm_h(const __half* __restrict__ A, const float* __restrict__ W,
            __half* __restrict__ Ch, int nrows) {
  __shared__ float Wl[128 * 128];
  gemm_body<true>(A, W, Ch, nrows, Wl, blockIdx.x);
}

// ---------- atomic-free CSR build (radix bucket by dst>>9) ----------
// R4-R6: 1.6M global atomics = ~103 us service floor + fill_csr ~40 us.
// Replaced by LDS-atomic bucket pipeline (no global atomic on the hot path).

// A: per-chunk histogram over 196 buckets -> cbc[chunk][bucket]
__global__ __launch_bounds__(256)
void bucket_count(const int* __restrict__ ei, int* __restrict__ cbc) {
  __shared__ int hist[NB];
  int t = threadIdx.x;
  int c = blockIdx.x;
  if (t < NB) hist[t] = 0;
  __syncthreads();
#pragma unroll
  for (int k = 0; k < EPB / 256; ++k) {
    int e = c * EPB + k * 256 + t;
    if (e < N_EDGES) atomicAdd(&hist[ei[N_EDGES + e] >> BSHIFT], 1);
  }
  __syncthreads();
  if (t < NB) cbc[c * NB + t] = hist[t];
}

// B: per-bucket scan over chunks + bucket-base scan -> cbc becomes global
// scatter offsets; bbase[b] = first edge slot of bucket b, bbase[NB]=E.
__global__ __launch_bounds__(256)
void bucket_scan(int* __restrict__ cbc, int* __restrict__ bbase) {
  int t = threadIdx.x;
  int total = 0;
  if (t < NB) {
    for (int c = 0; c < NCHUNKS; ++c) {
      int v = cbc[c * NB + t];
      cbc[c * NB + t] = total;
      total += v;
    }
  }
  __shared__ int s[256];
  s[t] = (t < NB) ? total : 0;
  __syncthreads();
#pragma unroll
  for (int d = 1; d < 256; d <<= 1) {
    int val = (t >= d) ? s[t - d] : 0;
    __syncthreads();
    s[t] += val;
    __syncthreads();
  }
  int excl = s[t] - ((t < NB) ? total : 0);
  if (t < NB) {
    bbase[t] = excl;
    if (t == NB - 1) bbase[NB] = excl + total;  // == N_EDGES
    for (int c = 0; c < NCHUNKS; ++c) cbc[c * NB + t] += excl;
  }
}

// C: scatter edges into bucket-ordered ebuf (LDS cursors, exactly-once)
__global__ __launch_bounds__(256)
void bucket_scatter(const int* __restrict__ ei, const int* __restrict__ cbc,
                    int2* __restrict__ ebuf) {
  __shared__ int cur[NB];
  int t = threadIdx.x;
  int c = blockIdx.x;
  if (t < NB) cur[t] = cbc[c * NB + t];
  __syncthreads();
#pragma unroll
  for (int k = 0; k < EPB / 256; ++k) {
    int e = c * EPB + k * 256 + t;
    if (e < N_EDGES) {
      int s = ei[e];
      int d = ei[N_EDGES + e];
      int p = atomicAdd(&cur[d >> BSHIFT], 1);
      ebuf[p] = make_int2(s, d);
    }
  }
}

// D: one block per bucket: LDS 512-histogram + local scan -> off, dinv,
// and dst-sorted csrc in one pass pair.
__global__ __launch_bounds__(256)
void bucket_csr(const int2* __restrict__ ebuf, const int* __restrict__ bbase,
                int* __restrict__ off, float* __restrict__ dinv,
                int* __restrict__ csrc) {
  __shared__ int hist[BUCKW];
  __shared__ int cur[BUCKW];
  __shared__ int s[256];
  int t = threadIdx.x;
  int b = blockIdx.x;
  int node0 = b << BSHIFT;
  int ebeg = bbase[b], eend = bbase[b + 1];

  hist[t] = 0; hist[t + 256] = 0;
  __syncthreads();
  for (int e = ebeg + t; e < eend; e += 256)
    atomicAdd(&hist[ebuf[e].y - node0], 1);
  __syncthreads();

  // exclusive scan of 512 counts (thread t owns elems 2t, 2t+1)
  int a = hist[2 * t], bq = hist[2 * t + 1];
  int sum = a + bq;
  s[t] = sum;
  __syncthreads();
#pragma unroll
  for (int d = 1; d < 256; d <<= 1) {
    int val = (t >= d) ? s[t - d] : 0;
    __syncthreads();
    s[t] += val;
    __syncthreads();
  }
  int run = s[t] - sum;
  cur[2 * t] = run;
  cur[2 * t + 1] = run + a;

  int i0 = node0 + 2 * t, i1 = node0 + 2 * t + 1;
  if (i0 < N_NODES) {
    off[i0] = ebeg + run;
    dinv[i0] = rsqrtf((float)(a + 1));
  }
  if (i1 < N_NODES) {
    off[i1] = ebeg + run + a;
    dinv[i1] = rsqrtf((float)(bq + 1));
  }
  if (b == NB - 1 && t == 0) off[N_NODES] = N_EDGES;
  __syncthreads();

  for (int e = ebeg + t; e < eend; e += 256) {
    int2 ed = ebuf[e];
    int p = atomicAdd(&cur[ed.y - node0], 1);
    csrc[ebeg + p] = ed.x;
  }
}

// ---------- graph (pooling) ranges from SORTED batch — no atomics ----------
__global__ void gbound(const int* __restrict__ batch, int* __restrict__ goff) {
  int i = blockIdx.x * blockDim.x + threadIdx.x;
  if (i >= N_NODES) return;
  int b = batch[i];
  if (i == 0) {
    for (int g = 0; g <= b; ++g) goff[g] = 0;
  } else {
    int a = batch[i - 1];
    for (int g = a + 1; g <= b; ++g) goff[g] = i;
  }
  if (i == N_NODES - 1) {
    for (int g = b + 1; g <= NGRAPH; ++g) goff[g] = N_NODES;
  }
}

// ---------- aggregation (R6's best shape: wave/node, 256 B row gathers) ----
__global__ __launch_bounds__(256)
void aggregate(const __half* __restrict__ h, const int* __restrict__ off,
               const int* __restrict__ csrc, const float* __restrict__ dinv,
               const float* __restrict__ bias, __half* __restrict__ out) {
  int gid = blockIdx.x * blockDim.x + threadIdx.x;
  int node = gid >> 6;
  int lane = gid & 63;
  if (node >= N_NODES) return;
  const __half2* h2 = (const __half2*)h;

  int beg = off[node], end = off[node + 1];
  float a0 = 0.f, a1 = 0.f;
  float b0_ = 0.f, b1_ = 0.f;
  float c0 = 0.f, c1 = 0.f;
  float d0 = 0.f, d1 = 0.f;

  int e = beg;
  for (; e + 8 <= end; e += 8) {
    int s0 = csrc[e + 0], s1 = csrc[e + 1], s2 = csrc[e + 2], s3 = csrc[e + 3];
    int s4 = csrc[e + 4], s5 = csrc[e + 5], s6 = csrc[e + 6], s7 = csrc[e + 7];
    float w0 = dinv[s0], w1 = dinv[s1], w2 = dinv[s2], w3 = dinv[s3];
    float w4 = dinv[s4], w5 = dinv[s5], w6 = dinv[s6], w7 = dinv[s7];
    float2 f0 = __half22float2(h2[(size_t)s0 * 64 + lane]);
    float2 f1 = __half22float2(h2[(size_t)s1 * 64 + lane]);
    float2 f2 = __half22float2(h2[(size_t)s2 * 64 + lane]);
    float2 f3 = __half22float2(h2[(size_t)s3 * 64 + lane]);
    float2 f4 = __half22float2(h2[(size_t)s4 * 64 + lane]);
    float2 f5 = __half22float2(h2[(size_t)s5 * 64 + lane]);
    float2 f6 = __half22float2(h2[(size_t)s6 * 64 + lane]);
    float2 f7 = __half22float2(h2[(size_t)s7 * 64 + lane]);
    a0 = fmaf(w0, f0.x, a0); a1 = fmaf(w0, f0.y, a1);
    b0_ = fmaf(w1, f1.x, b0_); b1_ = fmaf(w1, f1.y, b1_);
    c0 = fmaf(w2, f2.x, c0); c1 = fmaf(w2, f2.y, c1);
    d0 = fmaf(w3, f3.x, d0); d1 = fmaf(w3, f3.y, d1);
    a0 = fmaf(w4, f4.x, a0); a1 = fmaf(w4, f4.y, a1);
    b0_ = fmaf(w5, f5.x, b0_); b1_ = fmaf(w5, f5.y, b1_);
    c0 = fmaf(w6, f6.x, c0); c1 = fmaf(w6, f6.y, c1);
    d0 = fmaf(w7, f7.x, d0); d1 = fmaf(w7, f7.y, d1);
  }
  if (e + 4 <= end) {
    int s0 = csrc[e + 0], s1 = csrc[e + 1], s2 = csrc[e + 2], s3 = csrc[e + 3];
    float w0 = dinv[s0], w1 = dinv[s1], w2 = dinv[s2], w3 = dinv[s3];
    float2 f0 = __half22float2(h2[(size_t)s0 * 64 + lane]);
    float2 f1 = __half22float2(h2[(size_t)s1 * 64 + lane]);
    float2 f2 = __half22float2(h2[(size_t)s2 * 64 + lane]);
    float2 f3 = __half22float2(h2[(size_t)s3 * 64 + lane]);
    a0 = fmaf(w0, f0.x, a0); a1 = fmaf(w0, f0.y, a1);
    b0_ = fmaf(w1, f1.x, b0_); b1_ = fmaf(w1, f1.y, b1_);
    c0 = fmaf(w2, f2.x, c0); c1 = fmaf(w2, f2.y, c1);
    d0 = fmaf(w3, f3.x, d0); d1 = fmaf(w3, f3.y, d1);
    e += 4;
  }
  if (e + 2 <= end) {
    int s0 = csrc[e + 0], s1 = csrc[e + 1];
    float w0 = dinv[s0], w1 = dinv[s1];
    float2 f0 = __half22float2(h2[(size_t)s0 * 64 + lane]);
    float2 f1 = __half22float2(h2[(size_t)s1 * 64 + lane]);
    a0 = fmaf(w0, f0.x, a0); a1 = fmaf(w0, f0.y, a1);
    b0_ = fmaf(w1, f1.x, b0_); b1_ = fmaf(w1, f1.y, b1_);
    e += 2;
  }
  if (e < end) {
    int s0 = csrc[e];
    float w0 = dinv[s0];
    float2 f0 = __half22float2(h2[(size_t)s0 * 64 + lane]);
    a0 = fmaf(w0, f0.x, a0); a1 = fmaf(w0, f0.y, a1);
  }

  float dv = dinv[node];
  float2 vs = __half22float2(h2[(size_t)node * 64 + lane]);
  float s0f = (a0 + b0_) + (c0 + d0) + dv * vs.x;
  float s1f = (a1 + b1_) + (c1 + d1) + dv * vs.y;

  float2 bb = ((const float2*)bias)[lane];
  float ox = elu1(fmaf(dv, s0f, bb.x));
  float oy = elu1(fmaf(dv, s1f, bb.y));
  ((__half2*)out)[(size_t)node * 64 + lane] = __floats2half2_rn(ox, oy);
}

// ---------- fused max-pool + linear head + softmax ----------
__global__ void pool_head(const __half* __restrict__ feat, const int* __restrict__ goff,
                          const float* __restrict__ Wl, const float* __restrict__ bl,
                          float* __restrict__ out) {
  int g = blockIdx.x;
  int t = threadIdx.x;
  int beg = goff[g], end = goff[g + 1];

  float m0 = -INFINITY, m1 = -INFINITY, m2 = -INFINITY, m3 = -INFINITY;
  int i = beg;
  for (; i + 4 <= end; i += 4) {
    m0 = fmaxf(m0, __half2float(feat[(size_t)(i + 0) * HDIM + t]));
    m1 = fmaxf(m1, __half2float(feat[(size_t)(i + 1) * HDIM + t]));
    m2 = fmaxf(m2, __half2float(feat[(size_t)(i + 2) * HDIM + t]));
    m3 = fmaxf(m3, __half2float(feat[(size_t)(i + 3) * HDIM + t]));
  }
  for (; i < end; ++i) m0 = fmaxf(m0, __half2float(feat[(size_t)i * HDIM + t]));
  float m = fmaxf(fmaxf(m0, m1), fmaxf(m2, m3));
  if (beg == end) m = 0.f;

  __shared__ float pl[HDIM];
  __shared__ float lg[NCLS];
  pl[t] = m;
  __syncthreads();

  if (t < NCLS) {
    float acc = bl[t];
#pragma unroll
    for (int f = 0; f < HDIM; ++f) acc = fmaf(pl[f], Wl[f * NCLS + t], acc);
    lg[t] = acc;
  }
  __syncthreads();

  if (t < NCLS) {
    float mx = lg[0];
#pragma unroll
    for (int c = 1; c < NCLS; ++c) mx = fmaxf(mx, lg[c]);
    float ssum = 0.f;
#pragma unroll
    for (int c = 0; c < NCLS; ++c) ssum += __expf(lg[c] - mx);
    out[g * NCLS + t] = __expf(lg[t] - mx) / ssum;
  }
}

// ---------- launch ----------

extern "C" void kernel_launch(void* const* d_in, const int* in_sizes, int n_in,
                              void* d_out, int out_size, void* d_ws, size_t ws_size,
                              hipStream_t stream) {
  const float* x    = (const float*)d_in[0];
  const int*   ei   = (const int*)d_in[1];
  const int*   batch= (const int*)d_in[2];
  const float* W0 = (const float*)d_in[3]; const float* b0 = (const float*)d_in[4];
  const float* W1 = (const float*)d_in[5]; const float* b1 = (const float*)d_in[6];
  const float* W2 = (const float*)d_in[7]; const float* b2 = (const float*)d_in[8];
  const float* Wl = (const float*)d_in[9]; const float* bl = (const float*)d_in[10];
  float* out = (float*)d_out;

  char* w = (char*)d_ws;
  auto alloc = [&](size_t bytes) {
    char* p = w;
    w += (bytes + 255) & ~(size_t)255;
    return p;
  };
  int*    cbc    = (int*)   alloc((size_t)NCHUNKS * NB * 4);
  int*    bbase  = (int*)   alloc((size_t)(NB + 1) * 4);
  int2*   ebuf   = (int2*)  alloc((size_t)N_EDGES * 8);
  int*    off    = (int*)   alloc((size_t)(N_NODES + 1) * 4);
  float*  dinv   = (float*) alloc((size_t)N_NODES * 4);
  int*    goff   = (int*)   alloc((size_t)(NGRAPH + 1) * 4);
  int*    csrc   = (int*)   alloc((size_t)N_EDGES * 4);
  __half* hbuf   = (__half*)alloc((size_t)N_NODES * HDIM * 2);
  __half* feat   = (__half*)alloc((size_t)N_NODES * HDIM * 2);

  // layer-0 GEMM (standalone again; R6's embedded atomics couldn't overlap)
  gemm_f<<<GEMM_BLOCKS, 256, 0, stream>>>(x, W0, hbuf, N_NODES);

  // atomic-free CSR build
  bucket_count<<<NCHUNKS, 256, 0, stream>>>(ei, cbc);
  bucket_scan<<<1, 256, 0, stream>>>(cbc, bbase);
  bucket_scatter<<<NCHUNKS, 256, 0, stream>>>(ei, cbc, ebuf);
  bucket_csr<<<NB, 256, 0, stream>>>(ebuf, bbase, off, dinv, csrc);

  gbound<<<(N_NODES + 255) / 256, 256, 0, stream>>>(batch, goff);

  const float* bs[3] = {b0, b1, b2};
  aggregate<<<((size_t)N_NODES * 64 + 255) / 256, 256, 0, stream>>>(
      hbuf, off, csrc, dinv, bs[0], feat);
  for (int l = 1; l < 3; ++l) {
    const float* Wcur = (l == 1) ? W1 : W2;
    gemm_h<<<GEMM_BLOCKS, 256, 0, stream>>>(feat, Wcur, hbuf, N_NODES);
    aggregate<<<((size_t)N_NODES * 64 + 255) / 256, 256, 0, stream>>>(
        hbuf, off, csrc, dinv, bs[l], feat);
  }

  pool_head<<<NGRAPH, 128, 0, stream>>>(feat, goff, Wl, bl, out);
}

// Round 10
// 435.393 us; speedup vs baseline: 3.0853x; 1.3181x over previous
//
#include <hip/hip_runtime.h>
#include <hip/hip_fp16.h>
#include <math.h>

#define N_NODES 100000
#define N_EDGES 1600000
#define HDIM    128
#define NCLS    10
#define NGRAPH  1000
#define GEMM_BLOCKS  ((N_NODES + 127) / 128)   // 782
// radix-bucket CSR build
#define BSHIFT   9
#define BUCKW    (1 << BSHIFT)                 // 512 nodes / bucket
#define NB       ((N_NODES + BUCKW - 1) >> BSHIFT)   // 196
#define EPB      8192                          // edges per chunk block
#define NCHUNKS  ((N_EDGES + EPB - 1) / EPB)   // 196

typedef _Float16 half8 __attribute__((ext_vector_type(8)));
typedef float    f32x4 __attribute__((ext_vector_type(4)));

static __device__ __forceinline__ float elu1(float x) {
  return x > 0.f ? x : (__expf(x) - 1.f);
}

// ---------- MFMA GEMM: Ch[n,128](fp16) = A[n,128] @ W[128,128] ----------
// R9: vector-ALU GEMM was 80 us at 15% occupancy (64 KB LDS) — structural
// 157 TF ceiling. Switch to v_mfma_f32_16x16x32_f16 (~2 PF pipe). W is
// rounded to fp16 (adds ~2^-11 rel, same scale as existing fp16 h/feat).
// Block = 4 waves x 32 rows = 128 rows. W staged once per block into LDS
// PRE-SWIZZLED in B-fragment order -> hot-loop ds_read_b128 is lane-linear
// (conflict-free). Verified layouts (m89/m120): A[m=lane&15][k=quad*8+j],
// B[n=lane&15][k=quad*8+j], D col=lane&15 row=quad*4+reg.
template <bool AHALF>
__device__ __forceinline__
void gemm_mfma_body(const void* __restrict__ Av, const float* __restrict__ W,
                    __half* __restrict__ Ch, int nrows, half8* WtF, int bid) {
  int tid = threadIdx.x;
  // stage: fragment f = (k0, nt, lane): value[j] = W[k0*32+quad*8+j][nt*16+(l&15)]
  for (int f = tid; f < 2048; f += 256) {
    int k0 = f >> 9;
    int rem = f & 511;
    int nt = rem >> 6;
    int l = rem & 63;
    int n = nt * 16 + (l & 15);
    int kbase = k0 * 32 + (l >> 4) * 8;
    half8 hb;
#pragma unroll
    for (int j = 0; j < 8; ++j) hb[j] = (_Float16)W[(kbase + j) * 128 + n];
    WtF[f] = hb;
  }
  __syncthreads();

  int wv = tid >> 6, lane = tid & 63;
  int quad = lane >> 4, l15 = lane & 15;
  int m0 = bid * 128 + wv * 32;
  int r0 = m0 + l15;      if (r0 > nrows - 1) r0 = nrows - 1;  // clamp; stores guarded
  int r1 = m0 + 16 + l15; if (r1 > nrows - 1) r1 = nrows - 1;

  f32x4 acc[2][8];
#pragma unroll
  for (int mt = 0; mt < 2; ++mt)
#pragma unroll
    for (int nt = 0; nt < 8; ++nt) acc[mt][nt] = (f32x4){0.f, 0.f, 0.f, 0.f};

#pragma unroll
  for (int k0 = 0; k0 < 4; ++k0) {
    int koff = k0 * 32 + quad * 8;
    half8 a0, a1;
    if constexpr (AHALF) {
      const __half* Ah = (const __half*)Av;
      a0 = *(const half8*)(Ah + (size_t)r0 * 128 + koff);
      a1 = *(const half8*)(Ah + (size_t)r1 * 128 + koff);
    } else {
      const float* p0 = (const float*)Av + (size_t)r0 * 128 + koff;
      const float* p1 = (const float*)Av + (size_t)r1 * 128 + koff;
      float4 x0 = *(const float4*)p0, y0 = *(const float4*)(p0 + 4);
      float4 x1 = *(const float4*)p1, y1 = *(const float4*)(p1 + 4);
      a0[0] = (_Float16)x0.x; a0[1] = (_Float16)x0.y;
      a0[2] = (_Float16)x0.z; a0[3] = (_Float16)x0.w;
      a0[4] = (_Float16)y0.x; a0[5] = (_Float16)y0.y;
      a0[6] = (_Float16)y0.z; a0[7] = (_Float16)y0.w;
      a1[0] = (_Float16)x1.x; a1[1] = (_Float16)x1.y;
      a1[2] = (_Float16)x1.z; a1[3] = (_Float16)x1.w;
      a1[4] = (_Float16)y1.x; a1[5] = (_Float16)y1.y;
      a1[6] = (_Float16)y1.z; a1[7] = (_Float16)y1.w;
    }
#pragma unroll
    for (int nt = 0; nt < 8; ++nt) {
      half8 b = WtF[(k0 * 8 + nt) * 64 + lane];
      acc[0][nt] = __builtin_amdgcn_mfma_f32_16x16x32_f16(a0, b, acc[0][nt], 0, 0, 0);
      acc[1][nt] = __builtin_amdgcn_mfma_f32_16x16x32_f16(a1, b, acc[1][nt], 0, 0, 0);
    }
  }

#pragma unroll
  for (int mt = 0; mt < 2; ++mt) {
#pragma unroll
    for (int r = 0; r < 4; ++r) {
      int row = m0 + mt * 16 + quad * 4 + r;
      if (row < nrows) {
#pragma unroll
        for (int nt = 0; nt < 8; ++nt) {
          Ch[(size_t)row * 128 + nt * 16 + l15] = __float2half(acc[mt][nt][r]);
        }
      }
    }
  }
}

__global__ __launch_bounds__(256)
void gemm_mfma_f(const float* __restrict__ A, const float* __restrict__ W,
                 __half* __restrict__ Ch, int nrows) {
  __shared__ half8 WtF[2048];  // 32 KB
  gemm_mfma_body<false>(A, W, Ch, nrows, WtF, blockIdx.x);
}

__global__ __launch_bounds__(256)
void gemm_mfma_h(const __half* __restrict__ A, const float* __restrict__ W,
                 __half* __restrict__ Ch, int nrows) {
  __shared__ half8 WtF[2048];  // 32 KB
  gemm_mfma_body<true>(A, W, Ch, nrows, WtF, blockIdx.x);
}

// ---------- atomic-free CSR build (radix bucket by dst>>9) ----------
// (R9 WIN: LDS-atomic bucket pipeline, no global atomics on the hot path.)

__global__ __launch_bounds__(256)
void bucket_count(const int* __restrict__ ei, int* __restrict__ cbc) {
  __shared__ int hist[NB];
  int t = threadIdx.x;
  int c = blockIdx.x;
  if (t < NB) hist[t] = 0;
  __syncthreads();
#pragma unroll
  for (int k = 0; k < EPB / 256; ++k) {
    int e = c * EPB + k * 256 + t;
    if (e < N_EDGES) atomicAdd(&hist[ei[N_EDGES + e] >> BSHIFT], 1);
  }
  __syncthreads();
  if (t < NB) cbc[c * NB + t] = hist[t];
}

__global__ __launch_bounds__(256)
void bucket_scan(int* __restrict__ cbc, int* __restrict__ bbase) {
  int t = threadIdx.x;
  int total = 0;
  if (t < NB) {
    for (int c = 0; c < NCHUNKS; ++c) {
      int v = cbc[c * NB + t];
      cbc[c * NB + t] = total;
      total += v;
    }
  }
  __shared__ int s[256];
  s[t] = (t < NB) ? total : 0;
  __syncthreads();
#pragma unroll
  for (int d = 1; d < 256; d <<= 1) {
    int val = (t >= d) ? s[t - d] : 0;
    __syncthreads();
    s[t] += val;
    __syncthreads();
  }
  int excl = s[t] - ((t < NB) ? total : 0);
  if (t < NB) {
    bbase[t] = excl;
    if (t == NB - 1) bbase[NB] = excl + total;  // == N_EDGES
    for (int c = 0; c < NCHUNKS; ++c) cbc[c * NB + t] += excl;
  }
}

__global__ __launch_bounds__(256)
void bucket_scatter(const int* __restrict__ ei, const int* __restrict__ cbc,
                    int2* __restrict__ ebuf) {
  __shared__ int cur[NB];
  int t = threadIdx.x;
  int c = blockIdx.x;
  if (t < NB) cur[t] = cbc[c * NB + t];
  __syncthreads();
#pragma unroll
  for (int k = 0; k < EPB / 256; ++k) {
    int e = c * EPB + k * 256 + t;
    if (e < N_EDGES) {
      int s = ei[e];
      int d = ei[N_EDGES + e];
      int p = atomicAdd(&cur[d >> BSHIFT], 1);
      ebuf[p] = make_int2(s, d);
    }
  }
}

__global__ __launch_bounds__(256)
void bucket_csr(const int2* __restrict__ ebuf, const int* __restrict__ bbase,
                int* __restrict__ off, float* __restrict__ dinv,
                int* __restrict__ csrc) {
  __shared__ int hist[BUCKW];
  __shared__ int cur[BUCKW];
  __shared__ int s[256];
  int t = threadIdx.x;
  int b = blockIdx.x;
  int node0 = b << BSHIFT;
  int ebeg = bbase[b], eend = bbase[b + 1];

  hist[t] = 0; hist[t + 256] = 0;
  __syncthreads();
  for (int e = ebeg + t; e < eend; e += 256)
    atomicAdd(&hist[ebuf[e].y - node0], 1);
  __syncthreads();

  int a = hist[2 * t], bq = hist[2 * t + 1];
  int sum = a + bq;
  s[t] = sum;
  __syncthreads();
#pragma unroll
  for (int d = 1; d < 256; d <<= 1) {
    int val = (t >= d) ? s[t - d] : 0;
    __syncthreads();
    s[t] += val;
    __syncthreads();
  }
  int run = s[t] - sum;
  cur[2 * t] = run;
  cur[2 * t + 1] = run + a;

  int i0 = node0 + 2 * t, i1 = node0 + 2 * t + 1;
  if (i0 < N_NODES) {
    off[i0] = ebeg + run;
    dinv[i0] = rsqrtf((float)(a + 1));
  }
  if (i1 < N_NODES) {
    off[i1] = ebeg + run + a;
    dinv[i1] = rsqrtf((float)(bq + 1));
  }
  if (b == NB - 1 && t == 0) off[N_NODES] = N_EDGES;
  __syncthreads();

  for (int e = ebeg + t; e < eend; e += 256) {
    int2 ed = ebuf[e];
    int p = atomicAdd(&cur[ed.y - node0], 1);
    csrc[ebeg + p] = ed.x;
  }
}

// ---------- graph (pooling) ranges from SORTED batch — no atomics ----------
__global__ void gbound(const int* __restrict__ batch, int* __restrict__ goff) {
  int i = blockIdx.x * blockDim.x + threadIdx.x;
  if (i >= N_NODES) return;
  int b = batch[i];
  if (i == 0) {
    for (int g = 0; g <= b; ++g) goff[g] = 0;
  } else {
    int a = batch[i - 1];
    for (int g = a + 1; g <= b; ++g) goff[g] = i;
  }
  if (i == N_NODES - 1) {
    for (int g = b + 1; g <= NGRAPH; ++g) goff[g] = N_NODES;
  }
}

// ---------- aggregation (R6's best shape: wave/node, 256 B row gathers) ----
__global__ __launch_bounds__(256)
void aggregate(const __half* __restrict__ h, const int* __restrict__ off,
               const int* __restrict__ csrc, const float* __restrict__ dinv,
               const float* __restrict__ bias, __half* __restrict__ out) {
  int gid = blockIdx.x * blockDim.x + threadIdx.x;
  int node = gid >> 6;
  int lane = gid & 63;
  if (node >= N_NODES) return;
  const __half2* h2 = (const __half2*)h;

  int beg = off[node], end = off[node + 1];
  float a0 = 0.f, a1 = 0.f;
  float b0_ = 0.f, b1_ = 0.f;
  float c0 = 0.f, c1 = 0.f;
  float d0 = 0.f, d1 = 0.f;

  int e = beg;
  for (; e + 8 <= end; e += 8) {
    int s0 = csrc[e + 0], s1 = csrc[e + 1], s2 = csrc[e + 2], s3 = csrc[e + 3];
    int s4 = csrc[e + 4], s5 = csrc[e + 5], s6 = csrc[e + 6], s7 = csrc[e + 7];
    float w0 = dinv[s0], w1 = dinv[s1], w2 = dinv[s2], w3 = dinv[s3];
    float w4 = dinv[s4], w5 = dinv[s5], w6 = dinv[s6], w7 = dinv[s7];
    float2 f0 = __half22float2(h2[(size_t)s0 * 64 + lane]);
    float2 f1 = __half22float2(h2[(size_t)s1 * 64 + lane]);
    float2 f2 = __half22float2(h2[(size_t)s2 * 64 + lane]);
    float2 f3 = __half22float2(h2[(size_t)s3 * 64 + lane]);
    float2 f4 = __half22float2(h2[(size_t)s4 * 64 + lane]);
    float2 f5 = __half22float2(h2[(size_t)s5 * 64 + lane]);
    float2 f6 = __half22float2(h2[(size_t)s6 * 64 + lane]);
    float2 f7 = __half22float2(h2[(size_t)s7 * 64 + lane]);
    a0 = fmaf(w0, f0.x, a0); a1 = fmaf(w0, f0.y, a1);
    b0_ = fmaf(w1, f1.x, b0_); b1_ = fmaf(w1, f1.y, b1_);
    c0 = fmaf(w2, f2.x, c0); c1 = fmaf(w2, f2.y, c1);
    d0 = fmaf(w3, f3.x, d0); d1 = fmaf(w3, f3.y, d1);
    a0 = fmaf(w4, f4.x, a0); a1 = fmaf(w4, f4.y, a1);
    b0_ = fmaf(w5, f5.x, b0_); b1_ = fmaf(w5, f5.y, b1_);
    c0 = fmaf(w6, f6.x, c0); c1 = fmaf(w6, f6.y, c1);
    d0 = fmaf(w7, f7.x, d0); d1 = fmaf(w7, f7.y, d1);
  }
  if (e + 4 <= end) {
    int s0 = csrc[e + 0], s1 = csrc[e + 1], s2 = csrc[e + 2], s3 = csrc[e + 3];
    float w0 = dinv[s0], w1 = dinv[s1], w2 = dinv[s2], w3 = dinv[s3];
    float2 f0 = __half22float2(h2[(size_t)s0 * 64 + lane]);
    float2 f1 = __half22float2(h2[(size_t)s1 * 64 + lane]);
    float2 f2 = __half22float2(h2[(size_t)s2 * 64 + lane]);
    float2 f3 = __half22float2(h2[(size_t)s3 * 64 + lane]);
    a0 = fmaf(w0, f0.x, a0); a1 = fmaf(w0, f0.y, a1);
    b0_ = fmaf(w1, f1.x, b0_); b1_ = fmaf(w1, f1.y, b1_);
    c0 = fmaf(w2, f2.x, c0); c1 = fmaf(w2, f2.y, c1);
    d0 = fmaf(w3, f3.x, d0); d1 = fmaf(w3, f3.y, d1);
    e += 4;
  }
  if (e + 2 <= end) {
    int s0 = csrc[e + 0], s1 = csrc[e + 1];
    float w0 = dinv[s0], w1 = dinv[s1];
    float2 f0 = __half22float2(h2[(size_t)s0 * 64 + lane]);
    float2 f1 = __half22float2(h2[(size_t)s1 * 64 + lane]);
    a0 = fmaf(w0, f0.x, a0); a1 = fmaf(w0, f0.y, a1);
    b0_ = fmaf(w1, f1.x, b0_); b1_ = fmaf(w1, f1.y, b1_);
    e += 2;
  }
  if (e < end) {
    int s0 = csrc[e];
    float w0 = dinv[s0];
    float2 f0 = __half22float2(h2[(size_t)s0 * 64 + lane]);
    a0 = fmaf(w0, f0.x, a0); a1 = fmaf(w0, f0.y, a1);
  }

  float dv = dinv[node];
  float2 vs = __half22float2(h2[(size_t)node * 64 + lane]);
  float s0f = (a0 + b0_) + (c0 + d0) + dv * vs.x;
  float s1f = (a1 + b1_) + (c1 + d1) + dv * vs.y;

  float2 bb = ((const float2*)bias)[lane];
  float ox = elu1(fmaf(dv, s0f, bb.x));
  float oy = elu1(fmaf(dv, s1f, bb.y));
  ((__half2*)out)[(size_t)node * 64 + lane] = __floats2half2_rn(ox, oy);
}

// ---------- fused max-pool + linear head + softmax ----------
__global__ void pool_head(const __half* __restrict__ feat, const int* __restrict__ goff,
                          const float* __restrict__ Wl, const float* __restrict__ bl,
                          float* __restrict__ out) {
  int g = blockIdx.x;
  int t = threadIdx.x;
  int beg = goff[g], end = goff[g + 1];

  float m0 = -INFINITY, m1 = -INFINITY, m2 = -INFINITY, m3 = -INFINITY;
  int i = beg;
  for (; i + 4 <= end; i += 4) {
    m0 = fmaxf(m0, __half2float(feat[(size_t)(i + 0) * HDIM + t]));
    m1 = fmaxf(m1, __half2float(feat[(size_t)(i + 1) * HDIM + t]));
    m2 = fmaxf(m2, __half2float(feat[(size_t)(i + 2) * HDIM + t]));
    m3 = fmaxf(m3, __half2float(feat[(size_t)(i + 3) * HDIM + t]));
  }
  for (; i < end; ++i) m0 = fmaxf(m0, __half2float(feat[(size_t)i * HDIM + t]));
  float m = fmaxf(fmaxf(m0, m1), fmaxf(m2, m3));
  if (beg == end) m = 0.f;

  __shared__ float pl[HDIM];
  __shared__ float lg[NCLS];
  pl[t] = m;
  __syncthreads();

  if (t < NCLS) {
    float acc = bl[t];
#pragma unroll
    for (int f = 0; f < HDIM; ++f) acc = fmaf(pl[f], Wl[f * NCLS + t], acc);
    lg[t] = acc;
  }
  __syncthreads();

  if (t < NCLS) {
    float mx = lg[0];
#pragma unroll
    for (int c = 1; c < NCLS; ++c) mx = fmaxf(mx, lg[c]);
    float ssum = 0.f;
#pragma unroll
    for (int c = 0; c < NCLS; ++c) ssum += __expf(lg[c] - mx);
    out[g * NCLS + t] = __expf(lg[t] - mx) / ssum;
  }
}

// ---------- launch ----------

extern "C" void kernel_launch(void* const* d_in, const int* in_sizes, int n_in,
                              void* d_out, int out_size, void* d_ws, size_t ws_size,
                              hipStream_t stream) {
  const float* x    = (const float*)d_in[0];
  const int*   ei   = (const int*)d_in[1];
  const int*   batch= (const int*)d_in[2];
  const float* W0 = (const float*)d_in[3]; const float* b0 = (const float*)d_in[4];
  const float* W1 = (const float*)d_in[5]; const float* b1 = (const float*)d_in[6];
  const float* W2 = (const float*)d_in[7]; const float* b2 = (const float*)d_in[8];
  const float* Wl = (const float*)d_in[9]; const float* bl = (const float*)d_in[10];
  float* out = (float*)d_out;

  char* w = (char*)d_ws;
  auto alloc = [&](size_t bytes) {
    char* p = w;
    w += (bytes + 255) & ~(size_t)255;
    return p;
  };
  int*    cbc    = (int*)   alloc((size_t)NCHUNKS * NB * 4);
  int*    bbase  = (int*)   alloc((size_t)(NB + 1) * 4);
  int2*   ebuf   = (int2*)  alloc((size_t)N_EDGES * 8);
  int*    off    = (int*)   alloc((size_t)(N_NODES + 1) * 4);
  float*  dinv   = (float*) alloc((size_t)N_NODES * 4);
  int*    goff   = (int*)   alloc((size_t)(NGRAPH + 1) * 4);
  int*    csrc   = (int*)   alloc((size_t)N_EDGES * 4);
  __half* hbuf   = (__half*)alloc((size_t)N_NODES * HDIM * 2);
  __half* feat   = (__half*)alloc((size_t)N_NODES * HDIM * 2);

  // layer-0 GEMM (MFMA)
  gemm_mfma_f<<<GEMM_BLOCKS, 256, 0, stream>>>(x, W0, hbuf, N_NODES);

  // atomic-free CSR build
  bucket_count<<<NCHUNKS, 256, 0, stream>>>(ei, cbc);
  bucket_scan<<<1, 256, 0, stream>>>(cbc, bbase);
  bucket_scatter<<<NCHUNKS, 256, 0, stream>>>(ei, cbc, ebuf);
  bucket_csr<<<NB, 256, 0, stream>>>(ebuf, bbase, off, dinv, csrc);

  gbound<<<(N_NODES + 255) / 256, 256, 0, stream>>>(batch, goff);

  const float* bs[3] = {b0, b1, b2};
  aggregate<<<((size_t)N_NODES * 64 + 255) / 256, 256, 0, stream>>>(
      hbuf, off, csrc, dinv, bs[0], feat);
  for (int l = 1; l < 3; ++l) {
    const float* Wcur = (l == 1) ? W1 : W2;
    gemm_mfma_h<<<GEMM_BLOCKS, 256, 0, stream>>>(feat, Wcur, hbuf, N_NODES);
    aggregate<<<((size_t)N_NODES * 64 + 255) / 256, 256, 0, stream>>>(
        hbuf, off, csrc, dinv, bs[l], feat);
  }

  pool_head<<<NGRAPH, 128, 0, stream>>>(feat, goff, Wl, bl, out);
}